// Round 7
// baseline (1383.301 us; speedup 1.0000x reference)
//
#include <hip/hip_runtime.h>
#include <math.h>

// ---------------------------------------------------------------------------
// BDH forward, MI355X. Round 16 = round 15 + (a) scores back to 256^2 tiles
// but WITH the counted-vmcnt pipeline (gemm_sc256), (b) xs array deleted:
// MODE 1 writes only qr; MODE 4 recovers xs = R(-theta)*qr in its epilogue
// (rope is a rotation; partner via __shfl_xor(qv,1)).
// Round-15 evidence: bank conflicts 4.72M->0 gave only -4% => LDS not the
// path. Remaining fit: staging-issue BW. Scores staged 590 MB in 57.5 us =
// 16.8 B/cyc/CU (global_load_lds fill ceiling). 256^2 tiles stage 320 MB
// (1.8x less); round-12's 256^2 failed only because it drained vmcnt(0)
// every step. Quadrant-store epilogue = round-12's verified layout.
//
// gemm_bt: C = A(MxK) * Bt(NxK)^T, 128x128 tile, BK=32, 4 waves x (4x4)
// mfma_f32_16x16x32_bf16, fp32 accum. global_load_lds(16B) staging.
// Counted-vmcnt 3-buffer pipeline (T4): stage(k+1) stays in flight ACROSS
// the barrier; vmcnt never drained to 0 in the main loop (m218).
//   pre: stage(0), stage(1)                      -> 8 outstanding
//   step k: vmcnt(4); s_barrier; stage(k+2) -> buf (k+2)%3; compute(k)
// T2 swizzle: LDS slot j of row r holds data chunk j ^ ((r>>1)&3); stage
// pre-swizzles the GLOBAL source (LDS dest linear); read slot qd^((l15>>1)&3).
// Layouts (learn_hip m89/m91):
//   A: lane m=l%16, k=8*(l/16)+e ; B: lane n=l%16, k=8*(l/16)+e
//   D: lane reg r: row=4*(l/16)+r, col=l%16
// ---------------------------------------------------------------------------

typedef __bf16 bf16;
typedef bf16  bf16x8 __attribute__((ext_vector_type(8)));
typedef float f32x4  __attribute__((ext_vector_type(4)));

#define BM 128
#define BN 128
#define BK 32
#define SW 32   // unpadded: required for global_load_lds lane-contiguity

typedef __attribute__((address_space(3))) unsigned int lds_uint;
typedef const __attribute__((address_space(1))) unsigned int glb_uint;

__device__ __forceinline__ void ld_g2l16(const void* g, void* l) {
  __builtin_amdgcn_global_load_lds((glb_uint*)g, (lds_uint*)l, 16, 0, 0);
}

__device__ __forceinline__ float block_sum256(float v) {
  __shared__ float sb[4];
#pragma unroll
  for (int o = 32; o > 0; o >>= 1) v += __shfl_down(v, o);
  __syncthreads();
  if ((threadIdx.x & 63) == 0) sb[threadIdx.x >> 6] = v;
  __syncthreads();
  return sb[0] + sb[1] + sb[2] + sb[3];
}

// MODE 1: relu+rope (inline sincos) -> qr(bf16, Cv) ONLY (xs not materialized)
// MODE 2: strict causal mask, bf16 store [fallback path]
// MODE 3: split-K x4 over causal range, fp32 partial store (ykvp);
//         z = head*4+slice, K range [slice*256, min(slice*256+256, m0+128))
// MODE 4: xy = relu(gemm) * inverse-rope(qr read via Dv) -> bf16 Cv
// MODE 5: fp32 store (plain)
// MODE 7: dec split-K partial, bf16 store: grid(combo32, tile16); combo=head*8+chunk
// z-offset (MODE<6): ptr += (z&3)*aZ + (z>>2)*aZ2
template <int MODE>
__global__ __launch_bounds__(256) void gemm_bt(
    const bf16* __restrict__ A, long lda, long aZ, long aZ2,
    const bf16* __restrict__ Bt, long ldb, long bZ, long bZ2,
    void* __restrict__ Cv, long ldc, long cZ,
    void* __restrict__ Dv, long dZ,
    int M, int N, int K) {
  int m0, n0;
  long z = blockIdx.z;
  if (MODE == 7) {
    const int combo = blockIdx.x;   // head*8+chunk, FASTEST
    z = combo;
    m0 = (blockIdx.y >> 1) * BM;
    n0 = (blockIdx.y & 1) * BN;
    A  += (combo & 7) * aZ + (combo >> 3) * aZ2;
    Bt += (combo & 7) * bZ + (combo >> 3) * bZ2;
  } else {
    m0 = blockIdx.y * BM;
    n0 = blockIdx.x * BN;
    if (MODE == 2 && n0 > m0) return;  // never read downstream (causal clamp)
    A  += (z & 3) * aZ + (z >> 2) * aZ2;
    Bt += (z & 3) * bZ + (z >> 2) * bZ2;
  }

  int kbeg = 0;
  int Keff = K;
  if (MODE == 3) {
    const int s = (int)(z & 3);      // K-slice
    kbeg = s * 256;
    const int kc = m0 + BM;          // causal extent (<= K=1024)
    Keff = (kbeg + 256 < kc) ? kbeg + 256 : kc;
    if (kbeg >= Keff) return;        // fully masked slice; never read by ln_rows
  }

  // triple-buffered: 3 x (8 KB A + 8 KB B) = 48 KB
  __shared__ __align__(16) bf16 As[3][BM * SW];
  __shared__ __align__(16) bf16 Bs[3][BN * SW];

  const int tid  = threadIdx.x;
  const int lane = tid & 63;
  const int wr   = (tid >> 6) >> 1;
  const int wc   = (tid >> 6) & 1;
  const int l15  = lane & 15;
  const int qd   = lane >> 4;
  // T2 swizzle read slot for data chunk qd
  const int rj   = qd ^ ((l15 >> 1) & 3);

  f32x4 acc[4][4] = {};

  const int srow = tid >> 2;        // 0..63
  // stage pre-swizzle: slot (tid&3) of row srow holds chunk (tid&3)^((srow>>1)&3)
  const int skc  = (((tid & 3) ^ ((tid >> 3) & 3))) * 8;  // elements
  const bf16* ap = A + (long)(m0 + srow) * lda + skc;
  const bf16* bp = Bt + (long)(n0 + srow) * ldb + skc;

  auto stage = [&](int buf, int k0) {
    char* AsB = (char*)&As[buf][0];
    char* BsB = (char*)&Bs[buf][0];
    ld_g2l16(ap + k0,            AsB + tid * 16);         // A rows 0..63
    ld_g2l16(ap + k0 + 64 * lda, AsB + 4096 + tid * 16);  // A rows 64..127
    ld_g2l16(bp + k0,            BsB + tid * 16);         // B rows 0..63
    ld_g2l16(bp + k0 + 64 * ldb, BsB + 4096 + tid * 16);  // B rows 64..127
  };
  auto compute = [&](int buf) {
    bf16x8 af[4], bfr[4];
#pragma unroll
    for (int i = 0; i < 4; i++)
      af[i] = *(const bf16x8*)&As[buf][(wr * 64 + i * 16 + l15) * SW + rj * 8];
#pragma unroll
    for (int j = 0; j < 4; j++)
      bfr[j] = *(const bf16x8*)&Bs[buf][(wc * 64 + j * 16 + l15) * SW + rj * 8];
    __builtin_amdgcn_s_setprio(1);
#pragma unroll
    for (int i = 0; i < 4; i++)
#pragma unroll
      for (int j = 0; j < 4; j++)
        acc[i][j] = __builtin_amdgcn_mfma_f32_16x16x32_bf16(af[i], bfr[j], acc[i][j], 0, 0, 0);
    __builtin_amdgcn_s_setprio(0);
  };

  const int nst = (Keff - kbeg) >> 5;  // K-steps (>= 4 in all uses)
  stage(0, kbeg);
  stage(1, kbeg + BK);
  int bc = 0;  // buffer of current step
  for (int k = 0; k < nst - 1; k++) {
    asm volatile("s_waitcnt vmcnt(4)" ::: "memory");
    __builtin_amdgcn_s_barrier();
    const int k2 = k + 2;
    if (k2 < nst) {
      int b2 = bc + 2; if (b2 >= 3) b2 -= 3;
      stage(b2, kbeg + k2 * BK);
    }
    compute(bc);
    bc = (bc + 1 == 3) ? 0 : bc + 1;
  }
  asm volatile("s_waitcnt vmcnt(0)" ::: "memory");
  __builtin_amdgcn_s_barrier();
  compute(bc);

#pragma unroll
  for (int i = 0; i < 4; i++) {
#pragma unroll
    for (int j = 0; j < 4; j++) {
#pragma unroll
      for (int r = 0; r < 4; r++) {
        const int row = m0 + wr * 64 + i * 16 + qd * 4 + r;
        const int col = n0 + wc * 64 + j * 16 + l15;
        float v = acc[i][j][r];
        if (MODE == 1) {
          float rv = fmaxf(v, 0.f);
          float pv = __shfl_xor(rv, 1);  // relu'd rope-pair partner (col^1, same row)
          // rope: p=col>>1, freq=2^(-p/256)/(2pi), phase=(t*freq mod 1)*2pi
          float freq = exp2f(-(float)(col >> 1) * (1.0f / 256.0f)) * 0.15915494309189535f;
          float ph = (float)row * freq;
          ph -= floorf(ph);
          float s, c;
          __sincosf(ph * 6.283185307179586f, &s, &c);
          float rot = (col & 1) ? pv : -pv;
          ((bf16*)Cv)[z * cZ + (long)row * ldc + col] = (bf16)(rv * c + rot * s);
        } else if (MODE == 2) {
          ((bf16*)Cv)[z * cZ + (long)row * ldc + col] = (bf16)((col < row) ? v : 0.f);
        } else if (MODE == 4) {
          float rv = fmaxf(v, 0.f);
          // inverse rope: xs = R(-theta) * qr  (qr read via Dv; partner via shfl)
          float qv = (float)((const bf16*)Dv)[z * dZ + (long)row * 8192 + col];
          float pqv = __shfl_xor(qv, 1);
          float freq = exp2f(-(float)(col >> 1) * (1.0f / 256.0f)) * 0.15915494309189535f;
          float ph = (float)row * freq;
          ph -= floorf(ph);
          float s, c;
          __sincosf(ph * 6.283185307179586f, &s, &c);
          float rot = (col & 1) ? -pqv : pqv;   // opposite sign vs forward
          float xv = qv * c + rot * s;
          ((bf16*)Cv)[z * cZ + (long)row * ldc + col] = (bf16)(rv * xv);
        } else if (MODE == 7) {
          ((bf16*)Cv)[z * cZ + (long)row * ldc + col] = (bf16)v;  // bf16 partial
        } else {  // 3, 5
          ((float*)Cv)[z * cZ + (long)row * ldc + col] = v;
        }
      }
    }
  }
}

// scores GEMM, 256x256 tile, counted-vmcnt 3-buffer pipeline:
// scpart[slice] = QR_head QR_head^T (K-slice). grid: 320 x 512 threads.
// wgid%8 = XCD = K-slice; j=wgid/8: head=j/10, tile=j%10 (lower-tri 4x4 of
// 256-tiles). 8 waves = 2(M) x 4(N); per wave 128x64 = acc[8][4].
// Staged bytes: 320 blocks x 1 MB = 320 MB (vs 590 MB at 128^2).
// Quadrant-store epilogue: round-12-verified 36-slot 128-tile scpart layout.
__global__ __launch_bounds__(512) void gemm_sc256(
    const bf16* __restrict__ QR, bf16* __restrict__ scpart) {
  const int wgid  = blockIdx.x;
  const int slice = wgid & 7;
  const int j     = wgid >> 3;        // 0..39
  const int head  = j / 10;
  const int tile  = j - head * 10;    // 0..9
  const int tr = (int)((sqrtf(8.f * tile + 1.f) - 1.f) * 0.5f);
  const int tc = tile - tr * (tr + 1) / 2;
  const int m0 = tr * 256, n0 = tc * 256;
  const bf16* Ab = QR + (long)head * 8388608 + (long)slice * 1024;

  // triple-buffered: 3 x (16 KB A + 16 KB B) = 96 KB
  __shared__ __align__(16) bf16 As[3][256 * SW];
  __shared__ __align__(16) bf16 Bs[3][256 * SW];

  const int tid  = threadIdx.x;
  const int lane = tid & 63;
  const int w    = tid >> 6;    // 0..7
  const int wr   = w >> 2;      // 0..1 : M half
  const int wc   = w & 3;       // 0..3 : N quarter
  const int l15  = lane & 15;
  const int qd   = lane >> 4;
  const int rj   = qd ^ ((l15 >> 1) & 3);   // T2 read slot

  f32x4 acc[8][4] = {};

  const int srow = tid >> 2;        // 0..127
  const int skc  = (((tid & 3) ^ ((tid >> 3) & 3))) * 8;  // pre-swizzled chunk
  const bf16* ap = Ab + (long)(m0 + srow) * 8192 + skc;
  const bf16* bp = Ab + (long)(n0 + srow) * 8192 + skc;

  auto stage = [&](int buf, int k0) {
    char* AsB = (char*)&As[buf][0];
    char* BsB = (char*)&Bs[buf][0];
    ld_g2l16(ap + k0,               AsB + tid * 16);         // A rows 0..127
    ld_g2l16(ap + k0 + 128L * 8192, AsB + 8192 + tid * 16);  // A rows 128..255
    ld_g2l16(bp + k0,               BsB + tid * 16);
    ld_g2l16(bp + k0 + 128L * 8192, BsB + 8192 + tid * 16);
  };
  auto compute = [&](int buf) {
    bf16x8 af[8], bfr[4];
#pragma unroll
    for (int i = 0; i < 8; i++)
      af[i] = *(const bf16x8*)&As[buf][(wr * 128 + i * 16 + l15) * SW + rj * 8];
#pragma unroll
    for (int jj = 0; jj < 4; jj++)
      bfr[jj] = *(const bf16x8*)&Bs[buf][(wc * 64 + jj * 16 + l15) * SW + rj * 8];
    __builtin_amdgcn_s_setprio(1);
#pragma unroll
    for (int i = 0; i < 8; i++)
#pragma unroll
      for (int jj = 0; jj < 4; jj++)
        acc[i][jj] = __builtin_amdgcn_mfma_f32_16x16x32_bf16(af[i], bfr[jj], acc[i][jj], 0, 0, 0);
    __builtin_amdgcn_s_setprio(0);
  };

  const int nst = 32;  // K=1024 / BK=32
  stage(0, 0);
  stage(1, BK);
  int bc = 0;
  for (int k = 0; k < nst - 1; k++) {
    asm volatile("s_waitcnt vmcnt(4)" ::: "memory");
    __builtin_amdgcn_s_barrier();
    const int k2 = k + 2;
    if (k2 < nst) {
      int b2 = bc + 2; if (b2 >= 3) b2 -= 3;
      stage(b2, k2 * BK);
    }
    compute(bc);
    bc = (bc + 1 == 3) ? 0 : bc + 1;
  }
  asm volatile("s_waitcnt vmcnt(0)" ::: "memory");
  __builtin_amdgcn_s_barrier();
  compute(bc);

  // quadrant store into 36-slot 128-tile layout (round-12 verified)
  const int R = tr * 2 + wr;
  const int C = tc * 2 + (wc >> 1);
  if (R < C) return;  // above-diagonal quadrant of a diagonal 256-tile
  bf16* outp = scpart + (((long)slice * 4 + head) * 36 + (long)R * (R + 1) / 2 + C) * 16384;
#pragma unroll
  for (int i = 0; i < 8; i++) {
#pragma unroll
    for (int jj = 0; jj < 4; jj++) {
#pragma unroll
      for (int r = 0; r < 4; r++) {
        const int lr = i * 16 + qd * 4 + r;           // 0..127
        const int lc = (wc & 1) * 64 + jj * 16 + l15; // 0..127
        outp[(long)lr * 128 + lc] = (bf16)acc[i][jj][r];
      }
    }
  }
}

// sum 8 bf16 split-K slices, apply strict-causal mask, bf16 store into sc.
// scpart layout: (slice*4+head)*589824 + tile*16384, bf16.
// grid (36*4, 4): blockIdx.x = tile*4 + quarter; bf16x8 (16B) loads.
__global__ void reduce_sc(const bf16* __restrict__ scpart, bf16* __restrict__ sc) {
  const int tile = blockIdx.x >> 2, q = blockIdx.x & 3, head = blockIdx.y;
  const int tr = (int)((sqrtf(8.f * tile + 1.f) - 1.f) * 0.5f);
  const int tc = tile - tr * (tr + 1) / 2;
  const long t0 = (long)head * 589824 + (long)tile * 16384;  // elems
  for (int g = q * 512 + threadIdx.x; g < q * 512 + 512; g += 256) {
    const int i = g * 8;             // 8 consecutive elems, same 128-row
    float s[8] = {};
#pragma unroll
    for (int sl = 0; sl < 8; sl++) {
      bf16x8 v = *(const bf16x8*)&scpart[(long)sl * 2359296 + t0 + i];
#pragma unroll
      for (int e = 0; e < 8; e++) s[e] += (float)v[e];
    }
    const int lr = i >> 7, lc = i & 127;
    const int grow = tr * 128 + lr, gcol = tc * 128 + lc;
    bf16x8 o;
#pragma unroll
    for (int e = 0; e < 8; e++) o[e] = (bf16)((gcol + e < grow) ? s[e] : 0.f);
    *(bf16x8*)&sc[(long)head * 1048576 + (long)grow * 1024 + gcol] = o;
  }
}

// out[c][r] = bf16(in[r][c]); fp32 input
__global__ void transpose_cvt(const float* __restrict__ in, bf16* __restrict__ out,
                              int R, int C, long inZ, long outZ) {
  in += (long)blockIdx.z * inZ;
  out += (long)blockIdx.z * outZ;
  __shared__ float tile[32][33];
  int c0 = blockIdx.x * 32, r0 = blockIdx.y * 32;
  int lc = threadIdx.x & 31, lr8 = threadIdx.x >> 5;
#pragma unroll
  for (int i = 0; i < 32; i += 8)
    tile[lr8 + i][lc] = in[(long)(r0 + lr8 + i) * C + c0 + lc];
  __syncthreads();
#pragma unroll
  for (int i = 0; i < 32; i += 8)
    out[(long)(c0 + lr8 + i) * R + r0 + lc] = (bf16)tile[lc][lr8 + i];
}

__global__ void embed_ln(const int* __restrict__ idx, const float* __restrict__ embed,
                         float* __restrict__ x, bf16* __restrict__ xb,
                         bf16* __restrict__ xT) {
  int t = blockIdx.x, d = threadIdx.x;
  float v = embed[(long)idx[t] * 256 + d];
  float m = block_sum256(v) * (1.0f / 256.0f);
  float c = v - m;
  float var = block_sum256(c * c) * (1.0f / 256.0f);
  float o = c * rsqrtf(var + 1e-5f);
  x[t * 256 + d] = o;
  xb[t * 256 + d] = (bf16)o;
  xT[d * 1024 + t] = (bf16)o;
}

// LN over summed ykv split-K partials. ykvp[(head*4+s), t, d] fp32; valid
// slices for row t: s = 0..(t>>8).
__global__ void ln_rows(const float* __restrict__ ykvp, bf16* __restrict__ out) {
  int r = blockIdx.x, d = threadIdx.x;   // r = head*1024 + t
  int h = r >> 10, t = r & 1023;
  int ns = (t >> 8) + 1;
  float v = 0.f;
  for (int s = 0; s < ns; s++)
    v += ykvp[((long)(h * 4 + s)) * 262144 + (long)t * 256 + d];
  float m = block_sum256(v) * (1.0f / 256.0f);
  float c = v - m;
  float var = block_sum256(c * c) * (1.0f / 256.0f);
  out[(long)r * 256 + d] = (bf16)(c * rsqrtf(var + 1e-5f));
}

__global__ void ln_fuse(const bf16* __restrict__ part, float* __restrict__ x,
                        bf16* __restrict__ xb, bf16* __restrict__ xT) {
  int t = blockIdx.x, d = threadIdx.x;
  float s = 0.f;
#pragma unroll
  for (int i = 0; i < 32; i++) s += (float)part[(long)i * 262144 + t * 256 + d];
  float m = block_sum256(s) * (1.0f / 256.0f);
  float c = s - m;
  float var = block_sum256(c * c) * (1.0f / 256.0f);
  float y = c * rsqrtf(var + 1e-5f);
  float zv = x[t * 256 + d] + y;
  m = block_sum256(zv) * (1.0f / 256.0f);
  c = zv - m;
  var = block_sum256(c * c) * (1.0f / 256.0f);
  float o = c * rsqrtf(var + 1e-5f);
  x[t * 256 + d] = o;
  xb[t * 256 + d] = (bf16)o;
  xT[d * 1024 + t] = (bf16)o;
}

extern "C" void kernel_launch(void* const* d_in, const int* in_sizes, int n_in,
                              void* d_out, int out_size, void* d_ws, size_t ws_size,
                              hipStream_t stream) {
  const int*   idx = (const int*)d_in[0];
  const float* emb = (const float*)d_in[1];
  float* out = (float*)d_out;   // fp32 logits
  char* ws  = (char*)d_ws;

  // workspace layout (bytes)
  bf16*  encT   = (bf16*)(ws + 0L);            // (h,8192,256)
  bf16*  encvT  = (bf16*)(ws + 16777216L);     // (h,8192,256)
  bf16*  decT   = (bf16*)(ws + 33554432L);     // (256,32768)
  bf16*  lmT    = (bf16*)(ws + 50331648L);     // (256,256)
  float* x      = (float*)(ws + 50462720L);    // (1024,256) f32
  bf16*  xb     = (bf16*)(ws + 51511296L);     // (1024,256)
  bf16*  xT     = (bf16*)(ws + 52035584L);     // (256,1024)
  bf16*  xy     = (bf16*)(ws + 52559872L);     // (h,1024,8192): MODE-4 output
  bf16*  qr     = (bf16*)(ws + 119668736L);    // (h,1024,8192): rope(xs), live all layer
  bf16*  sc     = (bf16*)(ws + 186777600L);    // (h,1024,1024), ends 194871296
  // [195166208 .. 232914944): scpart (8 slices,4 heads,36 tiles,128,128) bf16
  // = 37748736 B. Aliases (each dead before the next is written):
  //   scpart (gemm_sc256 -> reduce_sc)
  //   ykvp  (16,1024,256) f32 = 16.8 MB (gemm<3> -> ln_rows)
  //   part  (32,1024,256) bf16 = 16.8 MB (gemm<7> -> ln_fuse)
  bf16*  scpart = (bf16*)(ws + 195166208L);
  float* ykvp   = (float*)(ws + 195166208L);   // ends 211943424
  bf16*  part   = (bf16*)(ws + 195166208L);    // ends 211943424
  bf16*  ykvln  = (bf16*)(ws + 211943424L);    // (h,1024,256), ends 214040576
  const bool big = ws_size >= 232914944UL;     // room for scpart?

  transpose_cvt<<<dim3(256, 8, 4), dim3(256), 0, stream>>>((const float*)d_in[2], encT, 256, 8192, 2097152L, 2097152L);
  transpose_cvt<<<dim3(256, 8, 4), dim3(256), 0, stream>>>((const float*)d_in[3], encvT, 256, 8192, 2097152L, 2097152L);
  transpose_cvt<<<dim3(8, 1024, 1), dim3(256), 0, stream>>>((const float*)d_in[4], decT, 32768, 256, 0L, 0L);
  transpose_cvt<<<dim3(8, 8, 1), dim3(256), 0, stream>>>((const float*)d_in[5], lmT, 256, 256, 0L, 0L);
  embed_ln<<<dim3(1024), dim3(256), 0, stream>>>(idx, emb, x, xb, xT);

  for (int l = 0; l < 6; l++) {
    // qr = rope(relu(x @ encoder[h]))  [xs not materialized]
    gemm_bt<1><<<dim3(64, 8, 4), dim3(256), 0, stream>>>(
        xb, 256L, 0L, 0L, encT, 256L, 2097152L, 8388608L,
        (void*)qr, 8192L, 8388608L, (void*)0, 0L, 1024, 8192, 256);
    if (big) {
      // scores: 256^2 tiles + counted vmcnt, split-K x8 (bf16 partials)
      gemm_sc256<<<dim3(320), dim3(512), 0, stream>>>(qr, scpart);
      reduce_sc<<<dim3(144, 4), dim3(256), 0, stream>>>(scpart, sc);
    } else {
      gemm_bt<2><<<dim3(8, 8, 4), dim3(256), 0, stream>>>(
          qr, 8192L, 8388608L, 33554432L, qr, 8192L, 8388608L, 33554432L,
          (void*)sc, 1024L, 1048576L, (void*)0, 0L, 1024, 1024, 8192);
    }
    // ykv partials = sc @ x, split-K x4 over causal range (z = head*4+slice)
    gemm_bt<3><<<dim3(2, 8, 16), dim3(256), 0, stream>>>(
        sc, 1024L, 0L, 1048576L, xT, 1024L, 0L, 0L,
        (void*)ykvp, 256L, 262144L, (void*)0, 0L, 1024, 256, 1024);
    ln_rows<<<dim3(4096), dim3(256), 0, stream>>>(ykvp, ykvln);
    // xy = inverse_rope(qr) * relu(ykvln @ encoder_v[h]) -> xy buffer
    gemm_bt<4><<<dim3(64, 8, 4), dim3(256), 0, stream>>>(
        ykvln, 256L, 262144L, 1048576L, encvT, 256L, 2097152L, 8388608L,
        (void*)xy, 8192L, 8388608L, (void*)qr, 8388608L, 1024, 8192, 256);
    // yMLP partials (bf16): split-K x8 per head (32 combos), combo-fastest
    gemm_bt<7><<<dim3(32, 16), dim3(256), 0, stream>>>(
        xy, 8192L, 1024L, 8388608L, decT, 32768L, 1024L, 8192L,
        (void*)part, 256L, 262144L, (void*)0, 0L, 1024, 256, 1024);
    ln_fuse<<<dim3(1024), dim3(256), 0, stream>>>(part, x, xb, xT);
  }
  // logits = x @ lm_head -> d_out (fp32)
  gemm_bt<5><<<dim3(2, 8, 1), dim3(256), 0, stream>>>(
      xb, 256L, 0L, 0L, lmT, 256L, 0L, 0L,
      (void*)out, 256L, 0L, (void*)0, 0L, 1024, 256, 256);
}

// Round 8
// 1289.553 us; speedup vs baseline: 1.0727x; 1.0727x over previous
//
#include <hip/hip_runtime.h>
#include <math.h>

// ---------------------------------------------------------------------------
// BDH forward, MI355X. Round 17 = merge of the two proven configurations:
//   - scores path from ROUND 15 (gemm_bt<6>: 128^2 tile, split-K x8 bf16
//     partials, counted-vmcnt 3-buffer pipeline, T2 swizzle, 0 conflicts,
//     measured 57.5 us/dispatch) — round-16's 256^2 variant regressed
//     (1 block/CU = 2 waves/SIMD cannot cover barrier latency + 320-block
//     tail at 62.5% utilization) and is dropped.
//   - xs-deletion from ROUND 16 (MODE 1 writes only qr; MODE 4 recovers
//     xs = R(-theta)*qr via __shfl_xor + sincos) — validated, -34 us.
// Counter state at the 128^2 kernel: HBM 22%, MFMA 26%, VALU 19%, LDS
// conflicts 0, LDS-BW ~60% => at the 2-phase structural ceiling (m230:
// 682 TF). Next lever would be the 8-phase schedule (dedicated round).
//
// gemm_bt: C = A(MxK) * Bt(NxK)^T, 128x128 tile, BK=32, 4 waves x (4x4)
// mfma_f32_16x16x32_bf16, fp32 accum. global_load_lds(16B) staging.
// Counted-vmcnt 3-buffer pipeline (T4): stage(k+1) stays in flight ACROSS
// the barrier; vmcnt never drained to 0 in the main loop (m218).
//   pre: stage(0), stage(1)                      -> 8 outstanding
//   step k: vmcnt(4); s_barrier; stage(k+2) -> buf (k+2)%3; compute(k)
// T2 swizzle: LDS slot j of row r holds data chunk j ^ ((r>>1)&3); stage
// pre-swizzles the GLOBAL source (LDS dest linear); read slot qd^((l15>>1)&3).
// Layouts (learn_hip m89/m91):
//   A: lane m=l%16, k=8*(l/16)+e ; B: lane n=l%16, k=8*(l/16)+e
//   D: lane reg r: row=4*(l/16)+r, col=l%16
// ---------------------------------------------------------------------------

typedef __bf16 bf16;
typedef bf16  bf16x8 __attribute__((ext_vector_type(8)));
typedef float f32x4  __attribute__((ext_vector_type(4)));

#define BM 128
#define BN 128
#define BK 32
#define SW 32   // unpadded: required for global_load_lds lane-contiguity

typedef __attribute__((address_space(3))) unsigned int lds_uint;
typedef const __attribute__((address_space(1))) unsigned int glb_uint;

__device__ __forceinline__ void ld_g2l16(const void* g, void* l) {
  __builtin_amdgcn_global_load_lds((glb_uint*)g, (lds_uint*)l, 16, 0, 0);
}

__device__ __forceinline__ float block_sum256(float v) {
  __shared__ float sb[4];
#pragma unroll
  for (int o = 32; o > 0; o >>= 1) v += __shfl_down(v, o);
  __syncthreads();
  if ((threadIdx.x & 63) == 0) sb[threadIdx.x >> 6] = v;
  __syncthreads();
  return sb[0] + sb[1] + sb[2] + sb[3];
}

// MODE 1: relu+rope (inline sincos) -> qr(bf16, Cv) ONLY (xs not materialized)
// MODE 2: strict causal mask, bf16 store [fallback path]
// MODE 3: split-K x4 over causal range, fp32 partial store (ykvp);
//         z = head*4+slice, K range [slice*256, min(slice*256+256, m0+128))
// MODE 4: xy = relu(gemm) * inverse-rope(qr read via Dv) -> bf16 Cv
// MODE 5: fp32 store (plain)
// MODE 6: scores split-K x8 partial: grid(combo32, tile36), bf16 compact store
//         combo = head*8+slice -> XCD = combo%8 = slice (locality per XCD)
// MODE 7: dec split-K partial, bf16 store: grid(combo32, tile16); combo=head*8+chunk
// z-offset (MODE<6): ptr += (z&3)*aZ + (z>>2)*aZ2
template <int MODE>
__global__ __launch_bounds__(256) void gemm_bt(
    const bf16* __restrict__ A, long lda, long aZ, long aZ2,
    const bf16* __restrict__ Bt, long ldb, long bZ, long bZ2,
    void* __restrict__ Cv, long ldc, long cZ,
    void* __restrict__ Dv, long dZ,
    int M, int N, int K) {
  int m0, n0;
  long z = blockIdx.z;
  if (MODE == 6) {
    const int combo = blockIdx.x;   // head*8+slice, FASTEST -> XCD=slice
    const int tile  = blockIdx.y;   // 0..35 lower-tri tile
    const int tr = (int)((sqrtf(8.f * tile + 1.f) - 1.f) * 0.5f);
    const int tc = tile - tr * (tr + 1) / 2;
    m0 = tr * BM; n0 = tc * BN;
    A  += (long)(combo >> 3) * aZ2 + (long)(combo & 7) * aZ;
    Bt += (long)(combo >> 3) * bZ2 + (long)(combo & 7) * bZ;
  } else if (MODE == 7) {
    const int combo = blockIdx.x;   // head*8+chunk, FASTEST
    z = combo;
    m0 = (blockIdx.y >> 1) * BM;
    n0 = (blockIdx.y & 1) * BN;
    A  += (combo & 7) * aZ + (combo >> 3) * aZ2;
    Bt += (combo & 7) * bZ + (combo >> 3) * bZ2;
  } else {
    m0 = blockIdx.y * BM;
    n0 = blockIdx.x * BN;
    if (MODE == 2 && n0 > m0) return;  // never read downstream (causal clamp)
    A  += (z & 3) * aZ + (z >> 2) * aZ2;
    Bt += (z & 3) * bZ + (z >> 2) * bZ2;
  }

  int kbeg = 0;
  int Keff = K;
  if (MODE == 3) {
    const int s = (int)(z & 3);      // K-slice
    kbeg = s * 256;
    const int kc = m0 + BM;          // causal extent (<= K=1024)
    Keff = (kbeg + 256 < kc) ? kbeg + 256 : kc;
    if (kbeg >= Keff) return;        // fully masked slice; never read by ln_rows
  }

  // triple-buffered: 3 x (8 KB A + 8 KB B) = 48 KB
  __shared__ __align__(16) bf16 As[3][BM * SW];
  __shared__ __align__(16) bf16 Bs[3][BN * SW];

  const int tid  = threadIdx.x;
  const int lane = tid & 63;
  const int wr   = (tid >> 6) >> 1;
  const int wc   = (tid >> 6) & 1;
  const int l15  = lane & 15;
  const int qd   = lane >> 4;
  // T2 swizzle read slot for data chunk qd
  const int rj   = qd ^ ((l15 >> 1) & 3);

  f32x4 acc[4][4] = {};

  const int srow = tid >> 2;        // 0..63
  // stage pre-swizzle: slot (tid&3) of row srow holds chunk (tid&3)^((srow>>1)&3)
  const int skc  = (((tid & 3) ^ ((tid >> 3) & 3))) * 8;  // elements
  const bf16* ap = A + (long)(m0 + srow) * lda + skc;
  const bf16* bp = Bt + (long)(n0 + srow) * ldb + skc;

  auto stage = [&](int buf, int k0) {
    char* AsB = (char*)&As[buf][0];
    char* BsB = (char*)&Bs[buf][0];
    ld_g2l16(ap + k0,            AsB + tid * 16);         // A rows 0..63
    ld_g2l16(ap + k0 + 64 * lda, AsB + 4096 + tid * 16);  // A rows 64..127
    ld_g2l16(bp + k0,            BsB + tid * 16);         // B rows 0..63
    ld_g2l16(bp + k0 + 64 * ldb, BsB + 4096 + tid * 16);  // B rows 64..127
  };
  auto compute = [&](int buf) {
    bf16x8 af[4], bfr[4];
#pragma unroll
    for (int i = 0; i < 4; i++)
      af[i] = *(const bf16x8*)&As[buf][(wr * 64 + i * 16 + l15) * SW + rj * 8];
#pragma unroll
    for (int j = 0; j < 4; j++)
      bfr[j] = *(const bf16x8*)&Bs[buf][(wc * 64 + j * 16 + l15) * SW + rj * 8];
    __builtin_amdgcn_s_setprio(1);
#pragma unroll
    for (int i = 0; i < 4; i++)
#pragma unroll
      for (int j = 0; j < 4; j++)
        acc[i][j] = __builtin_amdgcn_mfma_f32_16x16x32_bf16(af[i], bfr[j], acc[i][j], 0, 0, 0);
    __builtin_amdgcn_s_setprio(0);
  };

  const int nst = (Keff - kbeg) >> 5;  // K-steps (>= 4 in all uses)
  stage(0, kbeg);
  stage(1, kbeg + BK);
  int bc = 0;  // buffer of current step
  for (int k = 0; k < nst - 1; k++) {
    // stage(k) complete; stage(k+1)'s 4 loads stay in flight ACROSS the
    // barrier (T4: never drain vmcnt to 0 in the main loop).
    asm volatile("s_waitcnt vmcnt(4)" ::: "memory");
    __builtin_amdgcn_s_barrier();
    const int k2 = k + 2;
    if (k2 < nst) {
      int b2 = bc + 2; if (b2 >= 3) b2 -= 3;
      stage(b2, kbeg + k2 * BK);
    }
    compute(bc);
    bc = (bc + 1 == 3) ? 0 : bc + 1;
  }
  asm volatile("s_waitcnt vmcnt(0)" ::: "memory");
  __builtin_amdgcn_s_barrier();
  compute(bc);

#pragma unroll
  for (int i = 0; i < 4; i++) {
#pragma unroll
    for (int j = 0; j < 4; j++) {
#pragma unroll
      for (int r = 0; r < 4; r++) {
        const int row = m0 + wr * 64 + i * 16 + qd * 4 + r;
        const int col = n0 + wc * 64 + j * 16 + l15;
        float v = acc[i][j][r];
        if (MODE == 1) {
          float rv = fmaxf(v, 0.f);
          float pv = __shfl_xor(rv, 1);  // relu'd rope-pair partner (col^1, same row)
          // rope: p=col>>1, freq=2^(-p/256)/(2pi), phase=(t*freq mod 1)*2pi
          float freq = exp2f(-(float)(col >> 1) * (1.0f / 256.0f)) * 0.15915494309189535f;
          float ph = (float)row * freq;
          ph -= floorf(ph);
          float s, c;
          __sincosf(ph * 6.283185307179586f, &s, &c);
          float rot = (col & 1) ? pv : -pv;
          ((bf16*)Cv)[z * cZ + (long)row * ldc + col] = (bf16)(rv * c + rot * s);
        } else if (MODE == 2) {
          ((bf16*)Cv)[z * cZ + (long)row * ldc + col] = (bf16)((col < row) ? v : 0.f);
        } else if (MODE == 4) {
          float rv = fmaxf(v, 0.f);
          // inverse rope: xs = R(-theta) * qr  (qr read via Dv; partner via shfl)
          float qv = (float)((const bf16*)Dv)[z * dZ + (long)row * 8192 + col];
          float pqv = __shfl_xor(qv, 1);
          float freq = exp2f(-(float)(col >> 1) * (1.0f / 256.0f)) * 0.15915494309189535f;
          float ph = (float)row * freq;
          ph -= floorf(ph);
          float s, c;
          __sincosf(ph * 6.283185307179586f, &s, &c);
          float rot = (col & 1) ? -pqv : pqv;   // opposite sign vs forward
          float xv = qv * c + rot * s;
          ((bf16*)Cv)[z * cZ + (long)row * ldc + col] = (bf16)(rv * xv);
        } else if (MODE == 6) {
          const int combo = blockIdx.x;  // head*8+slice
          long base = (((long)(combo & 7) * 4 + (combo >> 3)) * 36 + blockIdx.y) * 16384;
          ((bf16*)Cv)[base + (long)(row - m0) * 128 + (col - n0)] = (bf16)v;
        } else if (MODE == 7) {
          ((bf16*)Cv)[z * cZ + (long)row * ldc + col] = (bf16)v;  // bf16 partial
        } else {  // 3, 5
          ((float*)Cv)[z * cZ + (long)row * ldc + col] = v;
        }
      }
    }
  }
}

// sum 8 bf16 split-K slices, apply strict-causal mask, bf16 store into sc.
// scpart layout (from gemm_bt<6>): (slice*4+head)*589824 + tile*16384, bf16.
// grid (36*4, 4): blockIdx.x = tile*4 + quarter; bf16x8 (16B) loads.
__global__ void reduce_sc(const bf16* __restrict__ scpart, bf16* __restrict__ sc) {
  const int tile = blockIdx.x >> 2, q = blockIdx.x & 3, head = blockIdx.y;
  const int tr = (int)((sqrtf(8.f * tile + 1.f) - 1.f) * 0.5f);
  const int tc = tile - tr * (tr + 1) / 2;
  const long t0 = (long)head * 589824 + (long)tile * 16384;  // elems
  for (int g = q * 512 + threadIdx.x; g < q * 512 + 512; g += 256) {
    const int i = g * 8;             // 8 consecutive elems, same 128-row
    float s[8] = {};
#pragma unroll
    for (int sl = 0; sl < 8; sl++) {
      bf16x8 v = *(const bf16x8*)&scpart[(long)sl * 2359296 + t0 + i];
#pragma unroll
      for (int e = 0; e < 8; e++) s[e] += (float)v[e];
    }
    const int lr = i >> 7, lc = i & 127;
    const int grow = tr * 128 + lr, gcol = tc * 128 + lc;
    bf16x8 o;
#pragma unroll
    for (int e = 0; e < 8; e++) o[e] = (bf16)((gcol + e < grow) ? s[e] : 0.f);
    *(bf16x8*)&sc[(long)head * 1048576 + (long)grow * 1024 + gcol] = o;
  }
}

// out[c][r] = bf16(in[r][c]); fp32 input
__global__ void transpose_cvt(const float* __restrict__ in, bf16* __restrict__ out,
                              int R, int C, long inZ, long outZ) {
  in += (long)blockIdx.z * inZ;
  out += (long)blockIdx.z * outZ;
  __shared__ float tile[32][33];
  int c0 = blockIdx.x * 32, r0 = blockIdx.y * 32;
  int lc = threadIdx.x & 31, lr8 = threadIdx.x >> 5;
#pragma unroll
  for (int i = 0; i < 32; i += 8)
    tile[lr8 + i][lc] = in[(long)(r0 + lr8 + i) * C + c0 + lc];
  __syncthreads();
#pragma unroll
  for (int i = 0; i < 32; i += 8)
    out[(long)(c0 + lr8 + i) * R + r0 + lc] = (bf16)tile[lc][lr8 + i];
}

__global__ void embed_ln(const int* __restrict__ idx, const float* __restrict__ embed,
                         float* __restrict__ x, bf16* __restrict__ xb,
                         bf16* __restrict__ xT) {
  int t = blockIdx.x, d = threadIdx.x;
  float v = embed[(long)idx[t] * 256 + d];
  float m = block_sum256(v) * (1.0f / 256.0f);
  float c = v - m;
  float var = block_sum256(c * c) * (1.0f / 256.0f);
  float o = c * rsqrtf(var + 1e-5f);
  x[t * 256 + d] = o;
  xb[t * 256 + d] = (bf16)o;
  xT[d * 1024 + t] = (bf16)o;
}

// LN over summed ykv split-K partials. ykvp[(head*4+s), t, d] fp32; valid
// slices for row t: s = 0..(t>>8).
__global__ void ln_rows(const float* __restrict__ ykvp, bf16* __restrict__ out) {
  int r = blockIdx.x, d = threadIdx.x;   // r = head*1024 + t
  int h = r >> 10, t = r & 1023;
  int ns = (t >> 8) + 1;
  float v = 0.f;
  for (int s = 0; s < ns; s++)
    v += ykvp[((long)(h * 4 + s)) * 262144 + (long)t * 256 + d];
  float m = block_sum256(v) * (1.0f / 256.0f);
  float c = v - m;
  float var = block_sum256(c * c) * (1.0f / 256.0f);
  out[(long)r * 256 + d] = (bf16)(c * rsqrtf(var + 1e-5f));
}

__global__ void ln_fuse(const bf16* __restrict__ part, float* __restrict__ x,
                        bf16* __restrict__ xb, bf16* __restrict__ xT) {
  int t = blockIdx.x, d = threadIdx.x;
  float s = 0.f;
#pragma unroll
  for (int i = 0; i < 32; i++) s += (float)part[(long)i * 262144 + t * 256 + d];
  float m = block_sum256(s) * (1.0f / 256.0f);
  float c = s - m;
  float var = block_sum256(c * c) * (1.0f / 256.0f);
  float y = c * rsqrtf(var + 1e-5f);
  float zv = x[t * 256 + d] + y;
  m = block_sum256(zv) * (1.0f / 256.0f);
  c = zv - m;
  var = block_sum256(c * c) * (1.0f / 256.0f);
  float o = c * rsqrtf(var + 1e-5f);
  x[t * 256 + d] = o;
  xb[t * 256 + d] = (bf16)o;
  xT[d * 1024 + t] = (bf16)o;
}

extern "C" void kernel_launch(void* const* d_in, const int* in_sizes, int n_in,
                              void* d_out, int out_size, void* d_ws, size_t ws_size,
                              hipStream_t stream) {
  const int*   idx = (const int*)d_in[0];
  const float* emb = (const float*)d_in[1];
  float* out = (float*)d_out;   // fp32 logits
  char* ws  = (char*)d_ws;

  // workspace layout (bytes)
  bf16*  encT   = (bf16*)(ws + 0L);            // (h,8192,256)
  bf16*  encvT  = (bf16*)(ws + 16777216L);     // (h,8192,256)
  bf16*  decT   = (bf16*)(ws + 33554432L);     // (256,32768)
  bf16*  lmT    = (bf16*)(ws + 50331648L);     // (256,256)
  float* x      = (float*)(ws + 50462720L);    // (1024,256) f32
  bf16*  xb     = (bf16*)(ws + 51511296L);     // (1024,256)
  bf16*  xT     = (bf16*)(ws + 52035584L);     // (256,1024)
  bf16*  xy     = (bf16*)(ws + 52559872L);     // (h,1024,8192): MODE-4 output
  bf16*  qr     = (bf16*)(ws + 119668736L);    // (h,1024,8192): rope(xs), live all layer
  bf16*  sc     = (bf16*)(ws + 186777600L);    // (h,1024,1024), ends 194871296
  // [195166208 .. 232914944): scpart (8 slices,4 heads,36 tiles,128,128) bf16
  // = 37748736 B. Aliases (each dead before the next is written):
  //   scpart (gemm<6> -> reduce_sc)
  //   ykvp  (16,1024,256) f32 = 16.8 MB (gemm<3> -> ln_rows)
  //   part  (32,1024,256) bf16 = 16.8 MB (gemm<7> -> ln_fuse)
  bf16*  scpart = (bf16*)(ws + 195166208L);
  float* ykvp   = (float*)(ws + 195166208L);   // ends 211943424
  bf16*  part   = (bf16*)(ws + 195166208L);    // ends 211943424
  bf16*  ykvln  = (bf16*)(ws + 211943424L);    // (h,1024,256), ends 214040576
  const bool big = ws_size >= 232914944UL;     // room for scpart?

  transpose_cvt<<<dim3(256, 8, 4), dim3(256), 0, stream>>>((const float*)d_in[2], encT, 256, 8192, 2097152L, 2097152L);
  transpose_cvt<<<dim3(256, 8, 4), dim3(256), 0, stream>>>((const float*)d_in[3], encvT, 256, 8192, 2097152L, 2097152L);
  transpose_cvt<<<dim3(8, 1024, 1), dim3(256), 0, stream>>>((const float*)d_in[4], decT, 32768, 256, 0L, 0L);
  transpose_cvt<<<dim3(8, 8, 1), dim3(256), 0, stream>>>((const float*)d_in[5], lmT, 256, 256, 0L, 0L);
  embed_ln<<<dim3(1024), dim3(256), 0, stream>>>(idx, emb, x, xb, xT);

  for (int l = 0; l < 6; l++) {
    // qr = rope(relu(x @ encoder[h]))  [xs not materialized]
    gemm_bt<1><<<dim3(64, 8, 4), dim3(256), 0, stream>>>(
        xb, 256L, 0L, 0L, encT, 256L, 2097152L, 8388608L,
        (void*)qr, 8192L, 8388608L, (void*)0, 0L, 1024, 8192, 256);
    if (big) {
      // scores split-K x8 (bf16 partials), combo-fastest grid (XCD=slice)
      gemm_bt<6><<<dim3(32, 36), dim3(256), 0, stream>>>(
          qr, 8192L, 1024L, 8388608L, qr, 8192L, 1024L, 8388608L,
          (void*)scpart, 0L, 0L, (void*)0, 0L, 1024, 1024, 1024);
      reduce_sc<<<dim3(144, 4), dim3(256), 0, stream>>>(scpart, sc);
    } else {
      gemm_bt<2><<<dim3(8, 8, 4), dim3(256), 0, stream>>>(
          qr, 8192L, 8388608L, 33554432L, qr, 8192L, 8388608L, 33554432L,
          (void*)sc, 1024L, 1048576L, (void*)0, 0L, 1024, 1024, 8192);
    }
    // ykv partials = sc @ x, split-K x4 over causal range (z = head*4+slice)
    gemm_bt<3><<<dim3(2, 8, 16), dim3(256), 0, stream>>>(
        sc, 1024L, 0L, 1048576L, xT, 1024L, 0L, 0L,
        (void*)ykvp, 256L, 262144L, (void*)0, 0L, 1024, 256, 1024);
    ln_rows<<<dim3(4096), dim3(256), 0, stream>>>(ykvp, ykvln);
    // xy = inverse_rope(qr) * relu(ykvln @ encoder_v[h]) -> xy buffer
    gemm_bt<4><<<dim3(64, 8, 4), dim3(256), 0, stream>>>(
        ykvln, 256L, 262144L, 1048576L, encvT, 256L, 2097152L, 8388608L,
        (void*)xy, 8192L, 8388608L, (void*)qr, 8388608L, 1024, 8192, 256);
    // yMLP partials (bf16): split-K x8 per head (32 combos), combo-fastest
    gemm_bt<7><<<dim3(32, 16), dim3(256), 0, stream>>>(
        xy, 8192L, 1024L, 8388608L, decT, 32768L, 1024L, 8192L,
        (void*)part, 256L, 262144L, (void*)0, 0L, 1024, 256, 1024);
    ln_fuse<<<dim3(1024), dim3(256), 0, stream>>>(part, x, xb, xT);
  }
  // logits = x @ lm_head -> d_out (fp32)
  gemm_bt<5><<<dim3(2, 8, 1), dim3(256), 0, stream>>>(
      xb, 256L, 0L, 0L, lmT, 256L, 0L, 0L,
      (void*)out, 256L, 0L, (void*)0, 0L, 1024, 256, 256);
}

// Round 9
// 1277.375 us; speedup vs baseline: 1.0829x; 1.0095x over previous
//
#include <hip/hip_runtime.h>
#include <math.h>

// ---------------------------------------------------------------------------
// BDH forward, MI355X. Round 18 = round 17 + wide-N (128x256) tiles for the
// two fat encoder GEMMs (MODE 1 -> gemm_wide<1>, MODE 4 -> gemm_wide<4>).
// Rationale: staged bytes = M*N*K*2*(1/BM+1/BN); at K=256 the (128,128) tile
// re-stages the tiny A panel 64x (268 MB/layer for ~19 MB of inputs).
// (128,256) cuts staging 25% and doubles MFMA-per-ds_read (32:12 vs 16:8).
// LDS 3x(8+16)KB = 72 KB -> 2 blocks/CU; acc[4][8] = 128 AGPR, launch_bounds
// (256,2) caps regs at 256 so residency holds. Swizzle/pipeline unchanged
// (vmcnt count 4->6 loads/stage). Scores kept at the round-15 config (58 us,
// 0 conflicts, = 2-phase ceiling); 8-phase 256^2 port rejected on block-
// granularity arithmetic (320 blocks x 1/CU -> 2 rounds = 64 us > 58).
//
// gemm_bt: C = A(MxK) * Bt(NxK)^T, 128x128 tile, BK=32, 4 waves x (4x4)
// mfma_f32_16x16x32_bf16, fp32 accum. global_load_lds(16B) staging.
// Counted-vmcnt 3-buffer pipeline (T4): stage(k+1) stays in flight ACROSS
// the barrier; vmcnt never drained to 0 in the main loop (m218).
// T2 swizzle: LDS slot j of row r holds data chunk j ^ ((r>>1)&3); stage
// pre-swizzles the GLOBAL source (LDS dest linear); read slot qd^((l15>>1)&3).
// Layouts (learn_hip m89/m91):
//   A: lane m=l%16, k=8*(l/16)+e ; B: lane n=l%16, k=8*(l/16)+e
//   D: lane reg r: row=4*(l/16)+r, col=l%16
// ---------------------------------------------------------------------------

typedef __bf16 bf16;
typedef bf16  bf16x8 __attribute__((ext_vector_type(8)));
typedef float f32x4  __attribute__((ext_vector_type(4)));

#define BM 128
#define BN 128
#define BK 32
#define SW 32   // unpadded: required for global_load_lds lane-contiguity

typedef __attribute__((address_space(3))) unsigned int lds_uint;
typedef const __attribute__((address_space(1))) unsigned int glb_uint;

__device__ __forceinline__ void ld_g2l16(const void* g, void* l) {
  __builtin_amdgcn_global_load_lds((glb_uint*)g, (lds_uint*)l, 16, 0, 0);
}

__device__ __forceinline__ float block_sum256(float v) {
  __shared__ float sb[4];
#pragma unroll
  for (int o = 32; o > 0; o >>= 1) v += __shfl_down(v, o);
  __syncthreads();
  if ((threadIdx.x & 63) == 0) sb[threadIdx.x >> 6] = v;
  __syncthreads();
  return sb[0] + sb[1] + sb[2] + sb[3];
}

// MODE 2: strict causal mask, bf16 store [fallback path]
// MODE 3: split-K x4 over causal range, fp32 partial store (ykvp);
//         z = head*4+slice, K range [slice*256, min(slice*256+256, m0+128))
// MODE 5: fp32 store (plain)
// MODE 6: scores split-K x8 partial: grid(combo32, tile36), bf16 compact store
//         combo = head*8+slice -> XCD = combo%8 = slice (locality per XCD)
// MODE 7: dec split-K partial, bf16 store: grid(combo32, tile16); combo=head*8+chunk
// z-offset (MODE<6): ptr += (z&3)*aZ + (z>>2)*aZ2
template <int MODE>
__global__ __launch_bounds__(256) void gemm_bt(
    const bf16* __restrict__ A, long lda, long aZ, long aZ2,
    const bf16* __restrict__ Bt, long ldb, long bZ, long bZ2,
    void* __restrict__ Cv, long ldc, long cZ,
    void* __restrict__ Dv, long dZ,
    int M, int N, int K) {
  int m0, n0;
  long z = blockIdx.z;
  if (MODE == 6) {
    const int combo = blockIdx.x;   // head*8+slice, FASTEST -> XCD=slice
    const int tile  = blockIdx.y;   // 0..35 lower-tri tile
    const int tr = (int)((sqrtf(8.f * tile + 1.f) - 1.f) * 0.5f);
    const int tc = tile - tr * (tr + 1) / 2;
    m0 = tr * BM; n0 = tc * BN;
    A  += (long)(combo >> 3) * aZ2 + (long)(combo & 7) * aZ;
    Bt += (long)(combo >> 3) * bZ2 + (long)(combo & 7) * bZ;
  } else if (MODE == 7) {
    const int combo = blockIdx.x;   // head*8+chunk, FASTEST
    z = combo;
    m0 = (blockIdx.y >> 1) * BM;
    n0 = (blockIdx.y & 1) * BN;
    A  += (combo & 7) * aZ + (combo >> 3) * aZ2;
    Bt += (combo & 7) * bZ + (combo >> 3) * bZ2;
  } else {
    m0 = blockIdx.y * BM;
    n0 = blockIdx.x * BN;
    if (MODE == 2 && n0 > m0) return;  // never read downstream (causal clamp)
    A  += (z & 3) * aZ + (z >> 2) * aZ2;
    Bt += (z & 3) * bZ + (z >> 2) * bZ2;
  }

  int kbeg = 0;
  int Keff = K;
  if (MODE == 3) {
    const int s = (int)(z & 3);      // K-slice
    kbeg = s * 256;
    const int kc = m0 + BM;          // causal extent (<= K=1024)
    Keff = (kbeg + 256 < kc) ? kbeg + 256 : kc;
    if (kbeg >= Keff) return;        // fully masked slice; never read by ln_rows
  }

  // triple-buffered: 3 x (8 KB A + 8 KB B) = 48 KB
  __shared__ __align__(16) bf16 As[3][BM * SW];
  __shared__ __align__(16) bf16 Bs[3][BN * SW];

  const int tid  = threadIdx.x;
  const int lane = tid & 63;
  const int wr   = (tid >> 6) >> 1;
  const int wc   = (tid >> 6) & 1;
  const int l15  = lane & 15;
  const int qd   = lane >> 4;
  // T2 swizzle read slot for data chunk qd
  const int rj   = qd ^ ((l15 >> 1) & 3);

  f32x4 acc[4][4] = {};

  const int srow = tid >> 2;        // 0..63
  // stage pre-swizzle: slot (tid&3) of row srow holds chunk (tid&3)^((srow>>1)&3)
  const int skc  = (((tid & 3) ^ ((tid >> 3) & 3))) * 8;  // elements
  const bf16* ap = A + (long)(m0 + srow) * lda + skc;
  const bf16* bp = Bt + (long)(n0 + srow) * ldb + skc;

  auto stage = [&](int buf, int k0) {
    char* AsB = (char*)&As[buf][0];
    char* BsB = (char*)&Bs[buf][0];
    ld_g2l16(ap + k0,            AsB + tid * 16);         // A rows 0..63
    ld_g2l16(ap + k0 + 64 * lda, AsB + 4096 + tid * 16);  // A rows 64..127
    ld_g2l16(bp + k0,            BsB + tid * 16);         // B rows 0..63
    ld_g2l16(bp + k0 + 64 * ldb, BsB + 4096 + tid * 16);  // B rows 64..127
  };
  auto compute = [&](int buf) {
    bf16x8 af[4], bfr[4];
#pragma unroll
    for (int i = 0; i < 4; i++)
      af[i] = *(const bf16x8*)&As[buf][(wr * 64 + i * 16 + l15) * SW + rj * 8];
#pragma unroll
    for (int j = 0; j < 4; j++)
      bfr[j] = *(const bf16x8*)&Bs[buf][(wc * 64 + j * 16 + l15) * SW + rj * 8];
    __builtin_amdgcn_s_setprio(1);
#pragma unroll
    for (int i = 0; i < 4; i++)
#pragma unroll
      for (int j = 0; j < 4; j++)
        acc[i][j] = __builtin_amdgcn_mfma_f32_16x16x32_bf16(af[i], bfr[j], acc[i][j], 0, 0, 0);
    __builtin_amdgcn_s_setprio(0);
  };

  const int nst = (Keff - kbeg) >> 5;  // K-steps (>= 4 in all uses)
  stage(0, kbeg);
  stage(1, kbeg + BK);
  int bc = 0;  // buffer of current step
  for (int k = 0; k < nst - 1; k++) {
    // stage(k) complete; stage(k+1)'s 4 loads stay in flight ACROSS the
    // barrier (T4: never drain vmcnt to 0 in the main loop).
    asm volatile("s_waitcnt vmcnt(4)" ::: "memory");
    __builtin_amdgcn_s_barrier();
    const int k2 = k + 2;
    if (k2 < nst) {
      int b2 = bc + 2; if (b2 >= 3) b2 -= 3;
      stage(b2, kbeg + k2 * BK);
    }
    compute(bc);
    bc = (bc + 1 == 3) ? 0 : bc + 1;
  }
  asm volatile("s_waitcnt vmcnt(0)" ::: "memory");
  __builtin_amdgcn_s_barrier();
  compute(bc);

#pragma unroll
  for (int i = 0; i < 4; i++) {
#pragma unroll
    for (int j = 0; j < 4; j++) {
#pragma unroll
      for (int r = 0; r < 4; r++) {
        const int row = m0 + wr * 64 + i * 16 + qd * 4 + r;
        const int col = n0 + wc * 64 + j * 16 + l15;
        float v = acc[i][j][r];
        if (MODE == 2) {
          ((bf16*)Cv)[z * cZ + (long)row * ldc + col] = (bf16)((col < row) ? v : 0.f);
        } else if (MODE == 6) {
          const int combo = blockIdx.x;  // head*8+slice
          long base = (((long)(combo & 7) * 4 + (combo >> 3)) * 36 + blockIdx.y) * 16384;
          ((bf16*)Cv)[base + (long)(row - m0) * 128 + (col - n0)] = (bf16)v;
        } else if (MODE == 7) {
          ((bf16*)Cv)[z * cZ + (long)row * ldc + col] = (bf16)v;  // bf16 partial
        } else {  // 3, 5
          ((float*)Cv)[z * cZ + (long)row * ldc + col] = v;
        }
      }
    }
  }
}

// Wide-N encoder GEMM: tile 128(M) x 256(N), K=256, BK=32, 4 waves (2Mx2N),
// per-wave 64x128 = acc[4][8] (128 AGPR). LDS 3x(8+16)KB = 72 KB -> 2 blk/CU;
// launch_bounds(256,2) caps regs at 256 so residency holds. Counted-vmcnt
// pipeline, 6 loads/stage -> vmcnt(6). Same T2 swizzle (row bits 1-2 = l15
// bits 1-2, invariant to the wider panel).
// MODE 1: C = rope(relu(A @ Bt^T))            (A=xb,   Bt=encT,  C=qr)
// MODE 4: C = relu(A @ Bt^T) * invrope(D)     (A=ykvln,Bt=encvT, C=xy, D=qr)
template <int MODE>
__global__ __launch_bounds__(256, 2) void gemm_wide(
    const bf16* __restrict__ A, long aZ,
    const bf16* __restrict__ Bt, long bZ,
    bf16* __restrict__ C, long cZ,
    const bf16* __restrict__ D, long dZ) {
  const long z  = blockIdx.z;          // head
  const int  m0 = blockIdx.y * 128;
  const int  n0 = blockIdx.x * 256;
  A  += z * aZ;
  Bt += z * bZ;

  __shared__ __align__(16) bf16 As[3][128 * SW];
  __shared__ __align__(16) bf16 Bs[3][256 * SW];

  const int tid  = threadIdx.x;
  const int lane = tid & 63;
  const int wr   = (tid >> 6) >> 1;   // 0..1 : M half
  const int wc   = (tid >> 6) & 1;    // 0..1 : N half
  const int l15  = lane & 15;
  const int qd   = lane >> 4;
  const int rj   = qd ^ ((l15 >> 1) & 3);

  f32x4 acc[4][8] = {};

  const int srow = tid >> 2;          // 0..63
  const int skc  = (((tid & 3) ^ ((tid >> 3) & 3))) * 8;
  const bf16* ap = A + (long)(m0 + srow) * 256 + skc;
  const bf16* bp = Bt + (long)(n0 + srow) * 256 + skc;

  auto stage = [&](int buf, int k0) {
    char* AsB = (char*)&As[buf][0];
    char* BsB = (char*)&Bs[buf][0];
    ld_g2l16(ap + k0,             AsB + tid * 16);          // A rows 0..63
    ld_g2l16(ap + k0 + 64 * 256,  AsB + 4096 + tid * 16);   // A rows 64..127
    ld_g2l16(bp + k0,             BsB + tid * 16);          // B rows 0..63
    ld_g2l16(bp + k0 + 64 * 256,  BsB + 4096 + tid * 16);   // B rows 64..127
    ld_g2l16(bp + k0 + 128 * 256, BsB + 8192 + tid * 16);   // B rows 128..191
    ld_g2l16(bp + k0 + 192 * 256, BsB + 12288 + tid * 16);  // B rows 192..255
  };
  auto compute = [&](int buf) {
    bf16x8 af[4], bfr[8];
#pragma unroll
    for (int i = 0; i < 4; i++)
      af[i] = *(const bf16x8*)&As[buf][(wr * 64 + i * 16 + l15) * SW + rj * 8];
#pragma unroll
    for (int j = 0; j < 8; j++)
      bfr[j] = *(const bf16x8*)&Bs[buf][(wc * 128 + j * 16 + l15) * SW + rj * 8];
    __builtin_amdgcn_s_setprio(1);
#pragma unroll
    for (int i = 0; i < 4; i++)
#pragma unroll
      for (int j = 0; j < 8; j++)
        acc[i][j] = __builtin_amdgcn_mfma_f32_16x16x32_bf16(af[i], bfr[j], acc[i][j], 0, 0, 0);
    __builtin_amdgcn_s_setprio(0);
  };

  const int nst = 8;  // K=256 / BK=32
  stage(0, 0);
  stage(1, BK);
  int bc = 0;
  for (int k = 0; k < nst - 1; k++) {
    asm volatile("s_waitcnt vmcnt(6)" ::: "memory");  // stage(k+1) in flight
    __builtin_amdgcn_s_barrier();
    const int k2 = k + 2;
    if (k2 < nst) {
      int b2 = bc + 2; if (b2 >= 3) b2 -= 3;
      stage(b2, k2 * BK);
    }
    compute(bc);
    bc = (bc + 1 == 3) ? 0 : bc + 1;
  }
  asm volatile("s_waitcnt vmcnt(0)" ::: "memory");
  __builtin_amdgcn_s_barrier();
  compute(bc);

#pragma unroll
  for (int i = 0; i < 4; i++) {
#pragma unroll
    for (int j = 0; j < 8; j++) {
#pragma unroll
      for (int r = 0; r < 4; r++) {
        const int row = m0 + wr * 64 + i * 16 + qd * 4 + r;
        const int col = n0 + wc * 128 + j * 16 + l15;
        float rv = fmaxf(acc[i][j][r], 0.f);
        float freq = exp2f(-(float)(col >> 1) * (1.0f / 256.0f)) * 0.15915494309189535f;
        float ph = (float)row * freq;
        ph -= floorf(ph);
        float s, c;
        __sincosf(ph * 6.283185307179586f, &s, &c);
        if (MODE == 1) {
          float pv = __shfl_xor(rv, 1);  // relu'd rope-pair partner
          float rot = (col & 1) ? pv : -pv;
          C[z * cZ + (long)row * 8192 + col] = (bf16)(rv * c + rot * s);
        } else {  // MODE 4
          float qv = (float)D[z * dZ + (long)row * 8192 + col];
          float pqv = __shfl_xor(qv, 1);
          float rot = (col & 1) ? -pqv : pqv;    // inverse rotation
          float xv = qv * c + rot * s;
          C[z * cZ + (long)row * 8192 + col] = (bf16)(rv * xv);
        }
      }
    }
  }
}

// sum 8 bf16 split-K slices, apply strict-causal mask, bf16 store into sc.
// scpart layout (from gemm_bt<6>): (slice*4+head)*589824 + tile*16384, bf16.
// grid (36*4, 4): blockIdx.x = tile*4 + quarter; bf16x8 (16B) loads.
__global__ void reduce_sc(const bf16* __restrict__ scpart, bf16* __restrict__ sc) {
  const int tile = blockIdx.x >> 2, q = blockIdx.x & 3, head = blockIdx.y;
  const int tr = (int)((sqrtf(8.f * tile + 1.f) - 1.f) * 0.5f);
  const int tc = tile - tr * (tr + 1) / 2;
  const long t0 = (long)head * 589824 + (long)tile * 16384;  // elems
  for (int g = q * 512 + threadIdx.x; g < q * 512 + 512; g += 256) {
    const int i = g * 8;             // 8 consecutive elems, same 128-row
    float s[8] = {};
#pragma unroll
    for (int sl = 0; sl < 8; sl++) {
      bf16x8 v = *(const bf16x8*)&scpart[(long)sl * 2359296 + t0 + i];
#pragma unroll
      for (int e = 0; e < 8; e++) s[e] += (float)v[e];
    }
    const int lr = i >> 7, lc = i & 127;
    const int grow = tr * 128 + lr, gcol = tc * 128 + lc;
    bf16x8 o;
#pragma unroll
    for (int e = 0; e < 8; e++) o[e] = (bf16)((gcol + e < grow) ? s[e] : 0.f);
    *(bf16x8*)&sc[(long)head * 1048576 + (long)grow * 1024 + gcol] = o;
  }
}

// out[c][r] = bf16(in[r][c]); fp32 input
__global__ void transpose_cvt(const float* __restrict__ in, bf16* __restrict__ out,
                              int R, int C, long inZ, long outZ) {
  in += (long)blockIdx.z * inZ;
  out += (long)blockIdx.z * outZ;
  __shared__ float tile[32][33];
  int c0 = blockIdx.x * 32, r0 = blockIdx.y * 32;
  int lc = threadIdx.x & 31, lr8 = threadIdx.x >> 5;
#pragma unroll
  for (int i = 0; i < 32; i += 8)
    tile[lr8 + i][lc] = in[(long)(r0 + lr8 + i) * C + c0 + lc];
  __syncthreads();
#pragma unroll
  for (int i = 0; i < 32; i += 8)
    out[(long)(c0 + lr8 + i) * R + r0 + lc] = (bf16)tile[lc][lr8 + i];
}

__global__ void embed_ln(const int* __restrict__ idx, const float* __restrict__ embed,
                         float* __restrict__ x, bf16* __restrict__ xb,
                         bf16* __restrict__ xT) {
  int t = blockIdx.x, d = threadIdx.x;
  float v = embed[(long)idx[t] * 256 + d];
  float m = block_sum256(v) * (1.0f / 256.0f);
  float c = v - m;
  float var = block_sum256(c * c) * (1.0f / 256.0f);
  float o = c * rsqrtf(var + 1e-5f);
  x[t * 256 + d] = o;
  xb[t * 256 + d] = (bf16)o;
  xT[d * 1024 + t] = (bf16)o;
}

// LN over summed ykv split-K partials. ykvp[(head*4+s), t, d] fp32; valid
// slices for row t: s = 0..(t>>8).
__global__ void ln_rows(const float* __restrict__ ykvp, bf16* __restrict__ out) {
  int r = blockIdx.x, d = threadIdx.x;   // r = head*1024 + t
  int h = r >> 10, t = r & 1023;
  int ns = (t >> 8) + 1;
  float v = 0.f;
  for (int s = 0; s < ns; s++)
    v += ykvp[((long)(h * 4 + s)) * 262144 + (long)t * 256 + d];
  float m = block_sum256(v) * (1.0f / 256.0f);
  float c = v - m;
  float var = block_sum256(c * c) * (1.0f / 256.0f);
  out[(long)r * 256 + d] = (bf16)(c * rsqrtf(var + 1e-5f));
}

__global__ void ln_fuse(const bf16* __restrict__ part, float* __restrict__ x,
                        bf16* __restrict__ xb, bf16* __restrict__ xT) {
  int t = blockIdx.x, d = threadIdx.x;
  float s = 0.f;
#pragma unroll
  for (int i = 0; i < 32; i++) s += (float)part[(long)i * 262144 + t * 256 + d];
  float m = block_sum256(s) * (1.0f / 256.0f);
  float c = s - m;
  float var = block_sum256(c * c) * (1.0f / 256.0f);
  float y = c * rsqrtf(var + 1e-5f);
  float zv = x[t * 256 + d] + y;
  m = block_sum256(zv) * (1.0f / 256.0f);
  c = zv - m;
  var = block_sum256(c * c) * (1.0f / 256.0f);
  float o = c * rsqrtf(var + 1e-5f);
  x[t * 256 + d] = o;
  xb[t * 256 + d] = (bf16)o;
  xT[d * 1024 + t] = (bf16)o;
}

extern "C" void kernel_launch(void* const* d_in, const int* in_sizes, int n_in,
                              void* d_out, int out_size, void* d_ws, size_t ws_size,
                              hipStream_t stream) {
  const int*   idx = (const int*)d_in[0];
  const float* emb = (const float*)d_in[1];
  float* out = (float*)d_out;   // fp32 logits
  char* ws  = (char*)d_ws;

  // workspace layout (bytes)
  bf16*  encT   = (bf16*)(ws + 0L);            // (h,8192,256)
  bf16*  encvT  = (bf16*)(ws + 16777216L);     // (h,8192,256)
  bf16*  decT   = (bf16*)(ws + 33554432L);     // (256,32768)
  bf16*  lmT    = (bf16*)(ws + 50331648L);     // (256,256)
  float* x      = (float*)(ws + 50462720L);    // (1024,256) f32
  bf16*  xb     = (bf16*)(ws + 51511296L);     // (1024,256)
  bf16*  xT     = (bf16*)(ws + 52035584L);     // (256,1024)
  bf16*  xy     = (bf16*)(ws + 52559872L);     // (h,1024,8192): MODE-4 output
  bf16*  qr     = (bf16*)(ws + 119668736L);    // (h,1024,8192): rope(xs), live all layer
  bf16*  sc     = (bf16*)(ws + 186777600L);    // (h,1024,1024), ends 194871296
  // [195166208 .. 232914944): scpart (8 slices,4 heads,36 tiles,128,128) bf16
  // = 37748736 B. Aliases (each dead before the next is written):
  //   scpart (gemm<6> -> reduce_sc)
  //   ykvp  (16,1024,256) f32 = 16.8 MB (gemm<3> -> ln_rows)
  //   part  (32,1024,256) bf16 = 16.8 MB (gemm<7> -> ln_fuse)
  bf16*  scpart = (bf16*)(ws + 195166208L);
  float* ykvp   = (float*)(ws + 195166208L);   // ends 211943424
  bf16*  part   = (bf16*)(ws + 195166208L);    // ends 211943424
  bf16*  ykvln  = (bf16*)(ws + 211943424L);    // (h,1024,256), ends 214040576
  const bool big = ws_size >= 232914944UL;     // room for scpart?

  transpose_cvt<<<dim3(256, 8, 4), dim3(256), 0, stream>>>((const float*)d_in[2], encT, 256, 8192, 2097152L, 2097152L);
  transpose_cvt<<<dim3(256, 8, 4), dim3(256), 0, stream>>>((const float*)d_in[3], encvT, 256, 8192, 2097152L, 2097152L);
  transpose_cvt<<<dim3(8, 1024, 1), dim3(256), 0, stream>>>((const float*)d_in[4], decT, 32768, 256, 0L, 0L);
  transpose_cvt<<<dim3(8, 8, 1), dim3(256), 0, stream>>>((const float*)d_in[5], lmT, 256, 256, 0L, 0L);
  embed_ln<<<dim3(1024), dim3(256), 0, stream>>>(idx, emb, x, xb, xT);

  for (int l = 0; l < 6; l++) {
    // qr = rope(relu(x @ encoder[h]))  [wide-N tile; xs not materialized]
    gemm_wide<1><<<dim3(32, 8, 4), dim3(256), 0, stream>>>(
        xb, 0L, encT, 2097152L, qr, 8388608L, (const bf16*)0, 0L);
    if (big) {
      // scores split-K x8 (bf16 partials), combo-fastest grid (XCD=slice)
      gemm_bt<6><<<dim3(32, 36), dim3(256), 0, stream>>>(
          qr, 8192L, 1024L, 8388608L, qr, 8192L, 1024L, 8388608L,
          (void*)scpart, 0L, 0L, (void*)0, 0L, 1024, 1024, 1024);
      reduce_sc<<<dim3(144, 4), dim3(256), 0, stream>>>(scpart, sc);
    } else {
      gemm_bt<2><<<dim3(8, 8, 4), dim3(256), 0, stream>>>(
          qr, 8192L, 8388608L, 33554432L, qr, 8192L, 8388608L, 33554432L,
          (void*)sc, 1024L, 1048576L, (void*)0, 0L, 1024, 1024, 8192);
    }
    // ykv partials = sc @ x, split-K x4 over causal range (z = head*4+slice)
    gemm_bt<3><<<dim3(2, 8, 16), dim3(256), 0, stream>>>(
        sc, 1024L, 0L, 1048576L, xT, 1024L, 0L, 0L,
        (void*)ykvp, 256L, 262144L, (void*)0, 0L, 1024, 256, 1024);
    ln_rows<<<dim3(4096), dim3(256), 0, stream>>>(ykvp, ykvln);
    // xy = inverse_rope(qr) * relu(ykvln @ encoder_v[h])  [wide-N tile]
    gemm_wide<4><<<dim3(32, 8, 4), dim3(256), 0, stream>>>(
        ykvln, 262144L, encvT, 2097152L, xy, 8388608L, qr, 8388608L);
    // yMLP partials (bf16): split-K x8 per head (32 combos), combo-fastest
    gemm_bt<7><<<dim3(32, 16), dim3(256), 0, stream>>>(
        xy, 8192L, 1024L, 8388608L, decT, 32768L, 1024L, 8192L,
        (void*)part, 256L, 262144L, (void*)0, 0L, 1024, 256, 1024);
    ln_fuse<<<dim3(1024), dim3(256), 0, stream>>>(part, x, xb, xT);
  }
  // logits = x @ lm_head -> d_out (fp32)
  gemm_bt<5><<<dim3(2, 8, 1), dim3(256), 0, stream>>>(
      xb, 256L, 0L, 0L, lmT, 256L, 0L, 0L,
      (void*)out, 256L, 0L, (void*)0, 0L, 1024, 256, 256);
}